// Round 1
// baseline (281.211 us; speedup 1.0000x reference)
//
#include <hip/hip_runtime.h>
#include <hip/hip_bf16.h>
#include <stdint.h>

// Problem constants (B=8192, D=256 fixed by reference setup_inputs)
#define NB 8192          // batch rows
#define ND 256           // feature dim
#define NW 16384         // rows of W = [v; u]
#define BM 128
#define BN 128
#define BK 64
#define INVT (1.0f / 0.07f)

typedef __bf16 bf16x8 __attribute__((ext_vector_type(8)));
typedef float floatx4 __attribute__((ext_vector_type(4)));

__device__ __forceinline__ void gload_lds16(const void* g, void* l) {
    // async global->LDS, 16B per lane; LDS dest = wave-uniform base + lane*16
    __builtin_amdgcn_global_load_lds(
        (const __attribute__((address_space(1))) unsigned int*)g,
        (__attribute__((address_space(3))) unsigned int*)l,
        16, 0, 0);
}

// ---------------------------------------------------------------------------
// Kernel 1: cast to bf16 into W=[v;u] (row-major 16384x256) and compute
// reciprocal norms rw[r] = 1/||row_r||.
// One block (256 threads) per row.
// ---------------------------------------------------------------------------
__global__ __launch_bounds__(256) void prep_kernel(
    const float* __restrict__ u, const float* __restrict__ v,
    __hip_bfloat16* __restrict__ W, float* __restrict__ rw)
{
    const int row = blockIdx.x;                       // 0..16383
    const float* src = (row < NB) ? (v + (size_t)row * ND)
                                  : (u + (size_t)(row - NB) * ND);
    const int t = threadIdx.x;                        // 0..255
    float x = src[t];
    W[(size_t)row * ND + t] = __float2bfloat16(x);
    float ss = x * x;
#pragma unroll
    for (int off = 32; off > 0; off >>= 1) ss += __shfl_down(ss, off, 64);
    __shared__ float wsum[4];
    if ((t & 63) == 0) wsum[t >> 6] = ss;
    __syncthreads();
    if (t == 0) {
        float tot = wsum[0] + wsum[1] + wsum[2] + wsum[3];
        rw[row] = rsqrtf(tot);                        // norms ~16, eps clamp moot
    }
}

// ---------------------------------------------------------------------------
// Kernel 2: fused tile GEMM + exp + per-row sum.
// Computes 128x128 tile of S = U @ W^T (bf16 MFMA), scales by ru_i*rw_j/T,
// excludes diagonals (uv diag -> pos[], uu diag -> dropped), exp, per-row
// partial sums -> atomicAdd into rowsum[8192].
// Grid: 64 row-tiles x 128 col-tiles = 8192 blocks x 256 threads (4 waves,
// 2x2 wave grid, 4x4 16x16 fragments per wave).
// ---------------------------------------------------------------------------
__global__ __launch_bounds__(256) void dcl_main(
    const __hip_bfloat16* __restrict__ W,   // 16384 x 256 (rows: v then u)
    const float* __restrict__ rw,           // 16384 inverse norms
    float* __restrict__ rowsum,             // 8192 (pre-zeroed)
    float* __restrict__ pos)                // 8192
{
    const int ct = blockIdx.x & 127;        // column tile 0..127
    const int rt = blockIdx.x >> 7;         // row tile 0..63
    const int rb = rt * BM;                 // row base in [0,8192)
    const int cb = ct * BN;                 // col base in [0,16384)

    const __hip_bfloat16* A = W + (size_t)NB * ND;   // u rows

    __shared__ __align__(16) __hip_bfloat16 As[BM * BK];  // 16 KB
    __shared__ __align__(16) __hip_bfloat16 Bs[BN * BK];  // 16 KB
    __shared__ float rowf[BM];
    __shared__ float colf[BN];

    const int tid  = threadIdx.x;
    const int wave = tid >> 6;
    const int lane = tid & 63;
    const int wm   = wave >> 1;
    const int wn   = wave & 1;
    const int quad = lane >> 4;             // 0..3
    const int tcol = lane & 15;             // 0..15

    if (tid < BM)       rowf[tid]       = rw[NB + rb + tid] * INVT;
    else                colf[tid - BM]  = rw[cb + (tid - BM)];

    floatx4 acc[4][4];
#pragma unroll
    for (int i = 0; i < 4; i++)
#pragma unroll
        for (int j = 0; j < 4; j++) acc[i][j] = (floatx4){0.f, 0.f, 0.f, 0.f};

    for (int kk = 0; kk < ND; kk += BK) {
        __syncthreads();   // protect LDS from previous iteration's readers
        // Stage A and B chunks (each 128x64 bf16 = 16 KB). Per wave: 4 issues
        // for A + 4 for B; lane l of issue i covers LDS bytes
        // o = wave*4096 + i*1024 + l*16.  Row = o>>7 (128 B/row), col byte = o&127.
#pragma unroll
        for (int i = 0; i < 4; i++) {
            int o = wave * 4096 + i * 1024 + lane * 16;
            int r = o >> 7;
            int c = o & 127;
            const __hip_bfloat16* ga = A + (size_t)(rb + r) * ND + kk + (c >> 1);
            gload_lds16(ga, (char*)As + wave * 4096 + i * 1024);
            const __hip_bfloat16* gb = W + (size_t)(cb + r) * ND + kk + (c >> 1);
            gload_lds16(gb, (char*)Bs + wave * 4096 + i * 1024);
        }
        __syncthreads();   // drains vmcnt (compiler inserts waitcnt before barrier)

#pragma unroll
        for (int ks = 0; ks < BK; ks += 32) {
            const int ko = ks + quad * 8;
            bf16x8 af[4], bfr[4];
#pragma unroll
            for (int mt = 0; mt < 4; mt++) {
                int r = wm * 64 + mt * 16 + tcol;      // A-operand: m = lane&15
                af[mt] = *(const bf16x8*)(&As[r * BK + ko]);
            }
#pragma unroll
            for (int nt = 0; nt < 4; nt++) {
                int r = wn * 64 + nt * 16 + tcol;      // B-operand: n = lane&15
                bfr[nt] = *(const bf16x8*)(&Bs[r * BK + ko]);
            }
#pragma unroll
            for (int mt = 0; mt < 4; mt++)
#pragma unroll
                for (int nt = 0; nt < 4; nt++)
                    acc[mt][nt] = __builtin_amdgcn_mfma_f32_16x16x32_bf16(
                        af[mt], bfr[nt], acc[mt][nt], 0, 0, 0);
        }
    }

    // Epilogue: C/D layout col=lane&15, row=quad*4+reg (verified m89/m91).
#pragma unroll
    for (int mt = 0; mt < 4; mt++) {
        float rsum[4] = {0.f, 0.f, 0.f, 0.f};
#pragma unroll
        for (int nt = 0; nt < 4; nt++) {
            const int lcol = wn * 64 + nt * 16 + tcol;
            const int gcol = cb + lcol;
            const float cf = colf[lcol];
#pragma unroll
            for (int reg = 0; reg < 4; reg++) {
                const int lrow = wm * 64 + mt * 16 + quad * 4 + reg;
                const int grow = rb + lrow;
                float s = acc[mt][nt][reg] * rowf[lrow] * cf;
                bool uvdiag = (gcol == grow);           // sim_uv diagonal -> pos
                bool uudiag = (gcol == grow + NB);      // sim_uu diagonal -> drop
                if (uvdiag) pos[grow] = s;
                rsum[reg] += (uvdiag || uudiag) ? 0.f : __expf(s);
            }
        }
        // reduce each row partial across the 16 lanes of this quad
#pragma unroll
        for (int reg = 0; reg < 4; reg++) {
            float vsum = rsum[reg];
            vsum += __shfl_xor(vsum, 1, 64);
            vsum += __shfl_xor(vsum, 2, 64);
            vsum += __shfl_xor(vsum, 4, 64);
            vsum += __shfl_xor(vsum, 8, 64);
            if (tcol == 0) {
                int grow = rb + wm * 64 + mt * 16 + quad * 4 + reg;
                atomicAdd(&rowsum[grow], vsum);
            }
        }
    }
}

// ---------------------------------------------------------------------------
// Kernel 3: loss = mean_i( log(rowsum_i) - pos_i )
// ---------------------------------------------------------------------------
__global__ __launch_bounds__(1024) void finalize_kernel(
    const float* __restrict__ rowsum, const float* __restrict__ pos,
    float* __restrict__ out)
{
    const int t = threadIdx.x;
    float s = 0.f;
    for (int i = t; i < NB; i += 1024) s += logf(rowsum[i]) - pos[i];
#pragma unroll
    for (int off = 32; off > 0; off >>= 1) s += __shfl_down(s, off, 64);
    __shared__ float wsum[16];
    if ((t & 63) == 0) wsum[t >> 6] = s;
    __syncthreads();
    if (t == 0) {
        float tot = 0.f;
#pragma unroll
        for (int i = 0; i < 16; i++) tot += wsum[i];
        out[0] = tot / (float)NB;
    }
}

extern "C" void kernel_launch(void* const* d_in, const int* in_sizes, int n_in,
                              void* d_out, int out_size, void* d_ws, size_t ws_size,
                              hipStream_t stream) {
    const float* u = (const float*)d_in[0];
    const float* v = (const float*)d_in[1];
    float* out = (float*)d_out;

    char* ws = (char*)d_ws;
    __hip_bfloat16* W = (__hip_bfloat16*)ws;                      // 8 MB
    float* rw     = (float*)(ws + (size_t)NW * ND * sizeof(__hip_bfloat16));
    float* rowsum = rw + NW;                                      // 8192 floats
    float* pos    = rowsum + NB;                                  // 8192 floats

    hipMemsetAsync(rowsum, 0, NB * sizeof(float), stream);
    prep_kernel<<<NW, 256, 0, stream>>>(u, v, W, rw);
    dcl_main<<<(NB / BM) * (NW / BN), 256, 0, stream>>>(W, rw, rowsum, pos);
    finalize_kernel<<<1, 1024, 0, stream>>>(rowsum, pos, out);
}